// Round 8
// baseline (793.595 us; speedup 1.0000x reference)
//
#include <hip/hip_runtime.h>
#include <hip/hip_bf16.h>
#include <math.h>

#define U_N   8192
#define I_N   16384
#define D_N   64
#define OUT_N 64
#define BN    32           // items per iteration tile
#define NCH   8            // item chunks (split-K)
#define ITERS 64           // (I_N/NCH)/BN
#define VN_ST 72           // Vn stride (halves): 144B rows, b128 reads 2-way-free
#define VT_ST 40           // Vt stride (halves): 80B rows, b128-aligned, 2-way-free
#define PL_ST 40           // P round-trip stride (halves)

typedef _Float16 half8  __attribute__((ext_vector_type(8)));
typedef short    bf16x8 __attribute__((ext_vector_type(8)));
typedef short    bf16x4 __attribute__((ext_vector_type(4)));
typedef float    f32x4  __attribute__((ext_vector_type(4)));
typedef int      int4v  __attribute__((ext_vector_type(4)));
typedef unsigned uint4v __attribute__((ext_vector_type(4)));

static __device__ __forceinline__ unsigned short f2bf(float f) {
    union { __hip_bfloat16 h; unsigned short u; } cv;
    cv.h = __float2bfloat16(f);
    return cv.u;
}
// LDS-only barrier: global prefetches stay in flight across it.
static __device__ __forceinline__ void bar() {
    asm volatile("s_waitcnt lgkmcnt(0)\n\ts_barrier" ::: "memory");
}

// ---------------------------------------------------------------------------
// pack_adj: the isolated HBM stream. Thread reads 512 B contiguous (128 items
// of one user), packs adj!=0 into 4 u32 words (bit b of word w = item 32w+b),
// writes dwordx4 to the tiled layout [u>>6][w4][u&63][4 words] so main's
// wave-reads are 256 B contiguous. Pure streaming -> fill-like efficiency.
// ---------------------------------------------------------------------------
__global__ __launch_bounds__(256)
void pack_adj(const int* __restrict__ adj, unsigned* __restrict__ mask)
{
    const int tid = blockIdx.x * 256 + threadIdx.x;   // U_N*128 threads
    const int u   = tid >> 7;                          // user
    const int w4  = tid & 127;                         // group of 4 words
    const int* src = adj + (size_t)u * I_N + w4 * 128;
    uint4v mw;
    #pragma unroll
    for (int j = 0; j < 4; ++j) {
        unsigned m = 0;
        #pragma unroll
        for (int i = 0; i < 8; ++i) {
            int4v v = *(const int4v*)(src + j * 32 + i * 4);
            m |= (v[0] != 0 ? (1u << (4 * i)) : 0u)
               | (v[1] != 0 ? (2u << (4 * i)) : 0u)
               | (v[2] != 0 ? (4u << (4 * i)) : 0u)
               | (v[3] != 0 ? (8u << (4 * i)) : 0u);
        }
        mw[j] = m;
    }
    *(uint4v*)&mask[((((size_t)u >> 6) * 128 + w4) * 64 + (u & 63)) * 4] = mw;
}

// ---------------------------------------------------------------------------
// prep_items: item_emb fp32 -> itemH f16 [item][dim] and itemTt bf16 tiled
// transpose [item>>5][dim][item&31].
// ---------------------------------------------------------------------------
__global__ __launch_bounds__(256)
void prep_items(const float* __restrict__ item,
                _Float16* __restrict__ itemH,
                unsigned short* __restrict__ itemTt)
{
    const int i = blockIdx.x * 256 + threadIdx.x;
    const float* src = item + (size_t)i * D_N;
    f32x4 v[16];
    #pragma unroll
    for (int j = 0; j < 16; ++j) v[j] = *(const f32x4*)(src + 4 * j);

    #pragma unroll
    for (int j = 0; j < 8; ++j) {
        half8 h;
        #pragma unroll
        for (int k = 0; k < 4; ++k) { h[k] = (_Float16)v[2*j][k]; h[4+k] = (_Float16)v[2*j+1][k]; }
        *(half8*)&itemH[(size_t)i * D_N + 8 * j] = h;
    }
    const size_t tb = (size_t)(i >> 5) * (D_N * 32) + (i & 31);
    #pragma unroll
    for (int d = 0; d < 64; ++d)
        itemTt[tb + (size_t)d * 32] = f2bf(v[d >> 2][d & 3]);
}

// ---------------------------------------------------------------------------
// Named-register pipeline state (arrays/structs/lambdas demote to scratch;
// r3/r4 lesson). Vectors with constant subscripts are safe.
// ---------------------------------------------------------------------------
#define DECL_SET(S) half8 vn##S; bf16x8 vt##S;

#define LOAD_TILE(S, tidx) do { \
    const size_t o_ = (size_t)(tidx) * BN; \
    vn##S = *(const half8*)&itemH[(ibase0 + o_ + (t >> 3)) * D_N + (t & 7) * 8]; \
    vt##S = *(const bf16x8*)&itemTt[((ibase0 + o_) >> 5) * (D_N * 32) \
                                    + (size_t)(t >> 2) * 32 + (t & 3) * 8]; \
} while (0)

#define COMMIT(S, bufw) do { \
    *(half8*)&Vn[bufw][(t >> 3) * VN_ST + (t & 7) * 8] = vn##S; \
    *(bf16x8*)&Vt[bufw][(t >> 2) * VT_ST + (t & 3) * 8] = vt##S; \
} while (0)

// S^T = Item * User^T (r7, verified). Lane (q,c) holds S^T[item][user=c];
// mask word mw covers this iter's 32 items: bit 4q+r = item 4q+r,
// bit 16+4q+r = item 16+4q+r -> ta = mw>>(4q): bits r and 16+r.
#define COMPUTE_REST(mw, bufr) do { \
    half8 a00 = *(const half8*)&Vn[bufr][(c)      * VN_ST      + q * 8]; \
    half8 a01 = *(const half8*)&Vn[bufr][(c)      * VN_ST + 32 + q * 8]; \
    half8 a10 = *(const half8*)&Vn[bufr][(16 + c) * VN_ST      + q * 8]; \
    half8 a11 = *(const half8*)&Vn[bufr][(16 + c) * VN_ST + 32 + q * 8]; \
    bf16x8 v0 = *(const bf16x8*)&Vt[bufr][(c)      * VT_ST + q * 8]; \
    bf16x8 v1 = *(const bf16x8*)&Vt[bufr][(16 + c) * VT_ST + q * 8]; \
    bf16x8 v2 = *(const bf16x8*)&Vt[bufr][(32 + c) * VT_ST + q * 8]; \
    bf16x8 v3 = *(const bf16x8*)&Vt[bufr][(48 + c) * VT_ST + q * 8]; \
    f32x4 T0 = (f32x4){0.f,0.f,0.f,0.f}; \
    f32x4 T1 = (f32x4){0.f,0.f,0.f,0.f}; \
    T0 = __builtin_amdgcn_mfma_f32_16x16x32_f16(a00, ufrag0, T0, 0, 0, 0); \
    T0 = __builtin_amdgcn_mfma_f32_16x16x32_f16(a01, ufrag1, T0, 0, 0, 0); \
    T1 = __builtin_amdgcn_mfma_f32_16x16x32_f16(a10, ufrag0, T1, 0, 0, 0); \
    T1 = __builtin_amdgcn_mfma_f32_16x16x32_f16(a11, ufrag1, T1, 0, 0, 0); \
    const unsigned ta_ = (mw) >> (4 * q); \
    bf16x4 p0, p1; \
    float e_; \
    e_ = __expf((ta_ & 0x1u)     ? T0[0] : 0.0f); p0[0] = (short)f2bf(e_); lc += e_; \
    e_ = __expf((ta_ & 0x2u)     ? T0[1] : 0.0f); p0[1] = (short)f2bf(e_); lc += e_; \
    e_ = __expf((ta_ & 0x4u)     ? T0[2] : 0.0f); p0[2] = (short)f2bf(e_); lc += e_; \
    e_ = __expf((ta_ & 0x8u)     ? T0[3] : 0.0f); p0[3] = (short)f2bf(e_); lc += e_; \
    e_ = __expf((ta_ & 0x10000u) ? T1[0] : 0.0f); p1[0] = (short)f2bf(e_); lc += e_; \
    e_ = __expf((ta_ & 0x20000u) ? T1[1] : 0.0f); p1[1] = (short)f2bf(e_); lc += e_; \
    e_ = __expf((ta_ & 0x40000u) ? T1[2] : 0.0f); p1[2] = (short)f2bf(e_); lc += e_; \
    e_ = __expf((ta_ & 0x80000u) ? T1[3] : 0.0f); p1[3] = (short)f2bf(e_); lc += e_; \
    *(bf16x4*)&plw[c * PL_ST + 4 * q]      = p0; \
    *(bf16x4*)&plw[c * PL_ST + 16 + 4 * q] = p1; \
    bf16x8 pf = *(const bf16x8*)&plw[c * PL_ST + q * 8]; \
    O0 = __builtin_amdgcn_mfma_f32_16x16x32_bf16(pf, v0, O0, 0, 0, 0); \
    O1 = __builtin_amdgcn_mfma_f32_16x16x32_bf16(pf, v1, O1, 0, 0, 0); \
    O2 = __builtin_amdgcn_mfma_f32_16x16x32_bf16(pf, v2, O2, 0, 0, 0); \
    O3 = __builtin_amdgcn_mfma_f32_16x16x32_bf16(pf, v3, O3, 0, 0, 0); \
} while (0)

#define PAIR(k, m0, m1) do { \
    COMMIT(B, 1); \
    LOAD_TILE(B, ((k) + 3 < ITERS) ? (k) + 3 : ITERS - 1); \
    COMPUTE_REST(m0, 0); \
    bar(); \
    COMMIT(A, 0); \
    LOAD_TILE(A, ((k) + 4 < ITERS) ? (k) + 4 : ITERS - 1); \
    COMPUTE_REST(m1, 1); \
    bar(); \
} while (0)

// ---------------------------------------------------------------------------
// Main: r7 pipeline (ping-pong LDS tiles, LDS-only barriers, transposed-S)
// minus all adj HBM traffic: masks come as one coalesced dwordx4 per lane per
// 4 iterations from the 16 MB L3-resident bitmask.
// ---------------------------------------------------------------------------
__global__ __launch_bounds__(256, 3)
void atten_main(const float* __restrict__ user_emb,
                const _Float16* __restrict__ itemH,
                const unsigned short* __restrict__ itemTt,
                const unsigned* __restrict__ mask,
                float* __restrict__ wsO,
                float* __restrict__ wsL)
{
    __shared__ _Float16 Vn[2][BN * VN_ST];
    __shared__ short    Vt[2][D_N * VT_ST];
    __shared__ unsigned short Pl[4][16 * PL_ST];

    const int ch   = blockIdx.x;
    const int ub   = blockIdx.y;
    const int t    = threadIdx.x;
    const int w    = t >> 6;
    const int lane = t & 63;
    const int c    = lane & 15;
    const int q    = lane >> 4;

    const int    urow0  = ub * 64 + w * 16;
    const size_t ibase0 = (size_t)ch * (I_N / NCH);
    const int    uu     = w * 16 + c;

    unsigned short* plw = &Pl[w][0];

    // per-lane mask base: tiled layout [ub][w4 = ch*16+hb][uu][4 words]
    const unsigned* mb = mask + ((size_t)(ub * 128 + ch * 16) * 64 + uu) * 4;

    half8 ufrag0, ufrag1;
    {
        const float* up = user_emb + (size_t)(urow0 + c) * D_N + q * 8;
        f32x4 a0 = *(const f32x4*)(up);
        f32x4 b0 = *(const f32x4*)(up + 4);
        f32x4 a1 = *(const f32x4*)(up + 32);
        f32x4 b1 = *(const f32x4*)(up + 36);
        #pragma unroll
        for (int j = 0; j < 4; ++j) {
            ufrag0[j] = (_Float16)a0[j]; ufrag0[4 + j] = (_Float16)b0[j];
            ufrag1[j] = (_Float16)a1[j]; ufrag1[4 + j] = (_Float16)b1[j];
        }
    }

    f32x4 O0 = (f32x4){0.f,0.f,0.f,0.f};
    f32x4 O1 = O0, O2 = O0, O3 = O0;
    float lc = 0.f;

    DECL_SET(A)
    DECL_SET(B)
    uint4v Mx, My;

    LOAD_TILE(A, 0);
    LOAD_TILE(B, 1);
    Mx = *(const uint4v*)&mb[0];       // words for iters 0..3
    My = *(const uint4v*)&mb[256];     // words for iters 4..7
    COMMIT(A, 0);
    LOAD_TILE(A, 2);
    bar();

    for (int hb = 0; hb < 16; hb += 2) {
        const int k0 = hb * 4;
        PAIR(k0,     Mx[0], Mx[1]);
        PAIR(k0 + 2, Mx[2], Mx[3]);
        Mx = *(const uint4v*)&mb[(size_t)((hb + 2 < 16) ? hb + 2 : 15) * 256];
        PAIR(k0 + 4, My[0], My[1]);
        PAIR(k0 + 6, My[2], My[3]);
        My = *(const uint4v*)&mb[(size_t)((hb + 3 < 16) ? hb + 3 : 15) * 256];
    }

    // l reduction: lanes c, c+16, c+32, c+48 hold partials for user c
    lc += __shfl_xor(lc, 16);
    lc += __shfl_xor(lc, 32);

    {
        float* d0 = wsO + ((size_t)ch * U_N + urow0 + 4 * q + 0) * D_N;
        float* d1 = wsO + ((size_t)ch * U_N + urow0 + 4 * q + 1) * D_N;
        float* d2 = wsO + ((size_t)ch * U_N + urow0 + 4 * q + 2) * D_N;
        float* d3 = wsO + ((size_t)ch * U_N + urow0 + 4 * q + 3) * D_N;
        d0[c] = O0[0]; d0[16 + c] = O1[0]; d0[32 + c] = O2[0]; d0[48 + c] = O3[0];
        d1[c] = O0[1]; d1[16 + c] = O1[1]; d1[32 + c] = O2[1]; d1[48 + c] = O3[1];
        d2[c] = O0[2]; d2[16 + c] = O1[2]; d2[32 + c] = O2[2]; d2[48 + c] = O3[2];
        d3[c] = O0[3]; d3[16 + c] = O1[3]; d3[32 + c] = O2[3]; d3[48 + c] = O3[3];
    }
    if (q == 0)
        wsL[(size_t)ch * U_N + urow0 + c] = lc;
}

// ---------------------------------------------------------------------------
// Combine: sum chunk partials, normalize, project by attention_weight.
// ---------------------------------------------------------------------------
__global__ __launch_bounds__(256)
void atten_combine(const float* __restrict__ wsO,
                   const float* __restrict__ wsL,
                   const float* __restrict__ attw,
                   float* __restrict__ out,
                   int nch)
{
    __shared__ float inv[64];
    __shared__ float agg[64][68];
    __shared__ float Wl[64][68];

    const int t  = threadIdx.x;
    const int u0 = blockIdx.x * 64;

    {
        const int d = t >> 2, o0 = (t & 3) * 16;
        const float* src = attw + d * OUT_N + o0;
        #pragma unroll
        for (int j = 0; j < 4; ++j)
            *(f32x4*)&Wl[d][o0 + 4 * j] = *(const f32x4*)(src + 4 * j);
    }
    if (t < 64) {
        float L = 0.f;
        for (int cc = 0; cc < nch; ++cc) L += wsL[(size_t)cc * U_N + u0 + t];
        inv[t] = 1.0f / L;
    }
    __syncthreads();

    {
        const int ul = t >> 2, d0 = (t & 3) * 16;
        const int u = u0 + ul;
        f32x4 a4[4];
        #pragma unroll
        for (int j = 0; j < 4; ++j) a4[j] = (f32x4){0.f, 0.f, 0.f, 0.f};
        for (int cc = 0; cc < nch; ++cc) {
            const float* src = wsO + ((size_t)cc * U_N + u) * D_N + d0;
            #pragma unroll
            for (int j = 0; j < 4; ++j) a4[j] += *(const f32x4*)(src + 4 * j);
        }
        const float s = inv[ul];
        #pragma unroll
        for (int j = 0; j < 4; ++j)
            *(f32x4*)&agg[ul][d0 + 4 * j] = a4[j] * s;
    }
    __syncthreads();

    {
        const int ul = t >> 2, o0 = (t & 3) * 16;
        f32x4 acc[4];
        #pragma unroll
        for (int j = 0; j < 4; ++j) acc[j] = (f32x4){0.f, 0.f, 0.f, 0.f};
        for (int d = 0; d < 64; ++d) {
            const float av = agg[ul][d];
            #pragma unroll
            for (int j = 0; j < 4; ++j) {
                f32x4 wv = *(const f32x4*)&Wl[d][o0 + 4 * j];
                acc[j] += wv * av;
            }
        }
        float* dst = out + (size_t)(u0 + ul) * OUT_N + o0;
        #pragma unroll
        for (int j = 0; j < 4; ++j)
            *(f32x4*)(dst + 4 * j) = acc[j];
    }
}

// ---------------------------------------------------------------------------
extern "C" void kernel_launch(void* const* d_in, const int* in_sizes, int n_in,
                              void* d_out, int out_size, void* d_ws, size_t ws_size,
                              hipStream_t stream)
{
    const float* user_emb = (const float*)d_in[0];
    const float* item_emb = (const float*)d_in[1];
    const float* attw     = (const float*)d_in[2];
    const int*   adj      = (const int*)d_in[3];
    float* out = (float*)d_out;

    // ws layout: wsO | wsL | itemH | itemTt | mask
    float*          wsO    = (float*)d_ws;
    float*          wsL    = wsO + (size_t)NCH * U_N * D_N;
    _Float16*       itemH  = (_Float16*)(wsL + (size_t)NCH * U_N);
    unsigned short* itemTt = (unsigned short*)(itemH + (size_t)I_N * D_N);
    unsigned*       mask   = (unsigned*)(itemTt + (size_t)I_N * D_N);

    pack_adj<<<dim3(U_N * 128 / 256), 256, 0, stream>>>(adj, mask);
    prep_items<<<dim3(I_N / 256), 256, 0, stream>>>(item_emb, itemH, itemTt);
    atten_main<<<dim3(NCH, U_N / 64), 256, 0, stream>>>(user_emb, itemH, itemTt, mask,
                                                        wsO, wsL);
    atten_combine<<<dim3(U_N / 64), 256, 0, stream>>>(wsO, wsL, attw, out, NCH);
}

// Round 9
// 740.693 us; speedup vs baseline: 1.0714x; 1.0714x over previous
//
#include <hip/hip_runtime.h>
#include <hip/hip_bf16.h>
#include <math.h>

#define U_N   8192
#define I_N   16384
#define D_N   64
#define OUT_N 64
#define BN    32           // items per iteration tile
#define NCH   16           // item chunks (split-K) -> 2048 blocks, 8/CU oversubscribed
#define ITERS 32           // (I_N/NCH)/BN
#define VN_ST 72           // Vn stride (halves): 144B rows, b128 reads 2-way-free
#define VT_ST 40           // Vt stride (halves): 80B rows, b64/b128-aligned

typedef _Float16 half8  __attribute__((ext_vector_type(8)));
typedef short    bf16x8 __attribute__((ext_vector_type(8)));
typedef short    bf16x4 __attribute__((ext_vector_type(4)));
typedef float    f32x4  __attribute__((ext_vector_type(4)));
typedef int      int4v  __attribute__((ext_vector_type(4)));

static __device__ __forceinline__ unsigned short f2bf(float f) {
    union { __hip_bfloat16 h; unsigned short u; } cv;
    cv.h = __float2bfloat16(f);
    return cv.u;
}
// LDS-only barrier: global prefetches stay in flight across it.
static __device__ __forceinline__ void bar() {
    asm volatile("s_waitcnt lgkmcnt(0)\n\ts_barrier" ::: "memory");
}
// PV matmul: 16x16x16 bf16. A-operand layout (row=lane&15, k=4*(lane>>4)+j)
// EXACTLY matches the S^T C-layout -> P feeds straight from registers.
static __device__ __forceinline__ f32x4 pv_mfma(bf16x4 a, bf16x4 b, f32x4 c) {
#if __has_builtin(__builtin_amdgcn_mfma_f32_16x16x16bf16_1k)
    return __builtin_amdgcn_mfma_f32_16x16x16bf16_1k(a, b, c, 0, 0, 0);
#else
    f32x4 d;
    asm volatile("v_mfma_f32_16x16x16_bf16 %0, %1, %2, %3"
                 : "=v"(d) : "v"(a), "v"(b), "v"(c));
    return d;
#endif
}

// ---------------------------------------------------------------------------
// prep_items: item_emb fp32 -> itemH f16 [item][dim] and itemTt bf16 tiled
// transpose [item>>5][dim][item&31].
// ---------------------------------------------------------------------------
__global__ __launch_bounds__(256)
void prep_items(const float* __restrict__ item,
                _Float16* __restrict__ itemH,
                unsigned short* __restrict__ itemTt)
{
    const int i = blockIdx.x * 256 + threadIdx.x;
    const float* src = item + (size_t)i * D_N;
    f32x4 v[16];
    #pragma unroll
    for (int j = 0; j < 16; ++j) v[j] = *(const f32x4*)(src + 4 * j);

    #pragma unroll
    for (int j = 0; j < 8; ++j) {
        half8 h;
        #pragma unroll
        for (int k = 0; k < 4; ++k) { h[k] = (_Float16)v[2*j][k]; h[4+k] = (_Float16)v[2*j+1][k]; }
        *(half8*)&itemH[(size_t)i * D_N + 8 * j] = h;
    }
    const size_t tb = (size_t)(i >> 5) * (D_N * 32) + (i & 31);
    #pragma unroll
    for (int d = 0; d < 64; ++d)
        itemTt[tb + (size_t)d * 32] = f2bf(v[d >> 2][d & 3]);
}

// ---------------------------------------------------------------------------
// Named-register pipeline state (arrays/structs/lambdas demote to scratch;
// r3/r4 lesson).
// ---------------------------------------------------------------------------
#define DECL_SET(S) \
    int4v adj##S##a, adj##S##b; \
    half8 vn##S; bf16x8 vt##S;

// lane (q,c): adj row urow0+c, items it*32 + 4q..4q+3 (a) and +16 (b)
#define LOAD_ADJ(S, tidx) do { \
    const size_t o_ = (size_t)(tidx) * BN; \
    adj##S##a = *(const int4v*)&adjq[o_];      \
    adj##S##b = *(const int4v*)&adjq[o_ + 16]; \
} while (0)

#define LOAD_TILE(S, tidx) do { \
    const size_t o_ = (size_t)(tidx) * BN; \
    vn##S = *(const half8*)&itemH[(ibase0 + o_ + (t >> 3)) * D_N + (t & 7) * 8]; \
    vt##S = *(const bf16x8*)&itemTt[((ibase0 + o_) >> 5) * (D_N * 32) \
                                    + (size_t)(t >> 2) * 32 + (t & 3) * 8]; \
} while (0)

#define COMMIT(S, bufw) do { \
    *(half8*)&Vn[bufw][(t >> 3) * VN_ST + (t & 7) * 8] = vn##S; \
    *(bf16x8*)&Vt[bufw][(t >> 2) * VT_ST + (t & 3) * 8] = vt##S; \
} while (0)

#define MASKS(S, ma, mb) \
    const unsigned ma = ((adj##S##a[0] != 0) ? 1u : 0u) | ((adj##S##a[1] != 0) ? 2u : 0u) | \
                        ((adj##S##a[2] != 0) ? 4u : 0u) | ((adj##S##a[3] != 0) ? 8u : 0u); \
    const unsigned mb = ((adj##S##b[0] != 0) ? 1u : 0u) | ((adj##S##b[1] != 0) ? 2u : 0u) | \
                        ((adj##S##b[2] != 0) ? 4u : 0u) | ((adj##S##b[3] != 0) ? 8u : 0u);

// S^T = Item * User^T (f16, K=32, from Vn). C gives lane (q,c):
// T0[r] = S^T[item 4q+r][user c], T1[r] = S^T[item 16+4q+r][user c].
// p0/p1 = exp(masked) packed bf16x4 -> DIRECT A-operands of pv_mfma
// (K-step0 = items 0..15, K-step1 = items 16..31). No LDS round-trip.
#define COMPUTE_REST(ma, mb, bufr) do { \
    half8 a00 = *(const half8*)&Vn[bufr][(c)      * VN_ST      + q * 8]; \
    half8 a01 = *(const half8*)&Vn[bufr][(c)      * VN_ST + 32 + q * 8]; \
    half8 a10 = *(const half8*)&Vn[bufr][(16 + c) * VN_ST      + q * 8]; \
    half8 a11 = *(const half8*)&Vn[bufr][(16 + c) * VN_ST + 32 + q * 8]; \
    f32x4 T0 = (f32x4){0.f,0.f,0.f,0.f}; \
    f32x4 T1 = (f32x4){0.f,0.f,0.f,0.f}; \
    T0 = __builtin_amdgcn_mfma_f32_16x16x32_f16(a00, ufrag0, T0, 0, 0, 0); \
    T0 = __builtin_amdgcn_mfma_f32_16x16x32_f16(a01, ufrag1, T0, 0, 0, 0); \
    T1 = __builtin_amdgcn_mfma_f32_16x16x32_f16(a10, ufrag0, T1, 0, 0, 0); \
    T1 = __builtin_amdgcn_mfma_f32_16x16x32_f16(a11, ufrag1, T1, 0, 0, 0); \
    bf16x4 p0, p1; \
    float e_; \
    e_ = __expf(((ma) & 1u) ? T0[0] : 0.0f); p0[0] = (short)f2bf(e_); lc += e_; \
    e_ = __expf(((ma) & 2u) ? T0[1] : 0.0f); p0[1] = (short)f2bf(e_); lc += e_; \
    e_ = __expf(((ma) & 4u) ? T0[2] : 0.0f); p0[2] = (short)f2bf(e_); lc += e_; \
    e_ = __expf(((ma) & 8u) ? T0[3] : 0.0f); p0[3] = (short)f2bf(e_); lc += e_; \
    e_ = __expf(((mb) & 1u) ? T1[0] : 0.0f); p1[0] = (short)f2bf(e_); lc += e_; \
    e_ = __expf(((mb) & 2u) ? T1[1] : 0.0f); p1[1] = (short)f2bf(e_); lc += e_; \
    e_ = __expf(((mb) & 4u) ? T1[2] : 0.0f); p1[2] = (short)f2bf(e_); lc += e_; \
    e_ = __expf(((mb) & 8u) ? T1[3] : 0.0f); p1[3] = (short)f2bf(e_); lc += e_; \
    bf16x4 vb00 = *(const bf16x4*)&Vt[bufr][(c)      * VT_ST      + 4 * q]; \
    bf16x4 vb01 = *(const bf16x4*)&Vt[bufr][(c)      * VT_ST + 16 + 4 * q]; \
    bf16x4 vb10 = *(const bf16x4*)&Vt[bufr][(16 + c) * VT_ST      + 4 * q]; \
    bf16x4 vb11 = *(const bf16x4*)&Vt[bufr][(16 + c) * VT_ST + 16 + 4 * q]; \
    bf16x4 vb20 = *(const bf16x4*)&Vt[bufr][(32 + c) * VT_ST      + 4 * q]; \
    bf16x4 vb21 = *(const bf16x4*)&Vt[bufr][(32 + c) * VT_ST + 16 + 4 * q]; \
    bf16x4 vb30 = *(const bf16x4*)&Vt[bufr][(48 + c) * VT_ST      + 4 * q]; \
    bf16x4 vb31 = *(const bf16x4*)&Vt[bufr][(48 + c) * VT_ST + 16 + 4 * q]; \
    O0 = pv_mfma(p0, vb00, O0);  O0 = pv_mfma(p1, vb01, O0); \
    O1 = pv_mfma(p0, vb10, O1);  O1 = pv_mfma(p1, vb11, O1); \
    O2 = pv_mfma(p0, vb20, O2);  O2 = pv_mfma(p1, vb21, O2); \
    O3 = pv_mfma(p0, vb30, O3);  O3 = pv_mfma(p1, vb31, O3); \
} while (0)

// ---------------------------------------------------------------------------
// Main: r7 pipeline (ping-pong LDS tiles, LDS-only barriers, transposed-S,
// adj streamed as dwordx4 pairs) with the P LDS round-trip replaced by the
// direct register feed into 16x16x16 bf16 PV MFMAs.
// ---------------------------------------------------------------------------
__global__ __launch_bounds__(256, 4)
void atten_main(const float* __restrict__ user_emb,
                const _Float16* __restrict__ itemH,
                const unsigned short* __restrict__ itemTt,
                const int*   __restrict__ adj,
                float* __restrict__ wsO,
                float* __restrict__ wsL)
{
    __shared__ _Float16 Vn[2][BN * VN_ST];
    __shared__ short    Vt[2][D_N * VT_ST];

    const int ch   = blockIdx.x;
    const int ub   = blockIdx.y;
    const int t    = threadIdx.x;
    const int w    = t >> 6;
    const int lane = t & 63;
    const int c    = lane & 15;
    const int q    = lane >> 4;

    const int    urow0  = ub * 64 + w * 16;
    const size_t ibase0 = (size_t)ch * (I_N / NCH);

    half8 ufrag0, ufrag1;
    {
        const float* up = user_emb + (size_t)(urow0 + c) * D_N + q * 8;
        f32x4 a0 = *(const f32x4*)(up);
        f32x4 b0 = *(const f32x4*)(up + 4);
        f32x4 a1 = *(const f32x4*)(up + 32);
        f32x4 b1 = *(const f32x4*)(up + 36);
        #pragma unroll
        for (int j = 0; j < 4; ++j) {
            ufrag0[j] = (_Float16)a0[j]; ufrag0[4 + j] = (_Float16)b0[j];
            ufrag1[j] = (_Float16)a1[j]; ufrag1[4 + j] = (_Float16)b1[j];
        }
    }

    f32x4 O0 = (f32x4){0.f,0.f,0.f,0.f};
    f32x4 O1 = O0, O2 = O0, O3 = O0;
    float lc = 0.f;

    const int* adjq = adj + (size_t)(urow0 + c) * I_N + ibase0 + 4 * q;

    DECL_SET(A)
    DECL_SET(B)

    LOAD_TILE(A, 0); LOAD_ADJ(A, 0);
    LOAD_TILE(B, 1); LOAD_ADJ(B, 1);
    COMMIT(A, 0);
    LOAD_TILE(A, 2);
    bar();

    for (int k = 0; k < ITERS; k += 2) {
        {
            MASKS(A, ma, mb)
            COMMIT(B, 1);
            const int ia = (k + 2 < ITERS) ? k + 2 : ITERS - 1;
            const int iv = (k + 3 < ITERS) ? k + 3 : ITERS - 1;
            LOAD_ADJ(A, ia);
            LOAD_TILE(B, iv);
            COMPUTE_REST(ma, mb, 0);
            bar();
        }
        {
            MASKS(B, ma, mb)
            COMMIT(A, 0);
            const int ia = (k + 3 < ITERS) ? k + 3 : ITERS - 1;
            const int iv = (k + 4 < ITERS) ? k + 4 : ITERS - 1;
            LOAD_ADJ(B, ia);
            LOAD_TILE(A, iv);
            COMPUTE_REST(ma, mb, 1);
            bar();
        }
    }

    // l lives per-lane for user c: reduce across the 4 quads
    lc += __shfl_xor(lc, 16);
    lc += __shfl_xor(lc, 32);

    // write chunk partials (O C-layout: lane (q,c): O[user? -> row 4q+r][dim 16nt+c])
    {
        float* d0 = wsO + ((size_t)ch * U_N + urow0 + 4 * q + 0) * D_N;
        float* d1 = wsO + ((size_t)ch * U_N + urow0 + 4 * q + 1) * D_N;
        float* d2 = wsO + ((size_t)ch * U_N + urow0 + 4 * q + 2) * D_N;
        float* d3 = wsO + ((size_t)ch * U_N + urow0 + 4 * q + 3) * D_N;
        d0[c] = O0[0]; d0[16 + c] = O1[0]; d0[32 + c] = O2[0]; d0[48 + c] = O3[0];
        d1[c] = O0[1]; d1[16 + c] = O1[1]; d1[32 + c] = O2[1]; d1[48 + c] = O3[1];
        d2[c] = O0[2]; d2[16 + c] = O1[2]; d2[32 + c] = O2[2]; d2[48 + c] = O3[2];
        d3[c] = O0[3]; d3[16 + c] = O1[3]; d3[32 + c] = O2[3]; d3[48 + c] = O3[3];
    }
    if (q == 0)
        wsL[(size_t)ch * U_N + urow0 + c] = lc;
}

// ---------------------------------------------------------------------------
// Combine: sum chunk partials, normalize, project by attention_weight.
// ---------------------------------------------------------------------------
__global__ __launch_bounds__(256)
void atten_combine(const float* __restrict__ wsO,
                   const float* __restrict__ wsL,
                   const float* __restrict__ attw,
                   float* __restrict__ out,
                   int nch)
{
    __shared__ float inv[64];
    __shared__ float agg[64][68];
    __shared__ float Wl[64][68];

    const int t  = threadIdx.x;
    const int u0 = blockIdx.x * 64;

    {
        const int d = t >> 2, o0 = (t & 3) * 16;
        const float* src = attw + d * OUT_N + o0;
        #pragma unroll
        for (int j = 0; j < 4; ++j)
            *(f32x4*)&Wl[d][o0 + 4 * j] = *(const f32x4*)(src + 4 * j);
    }
    if (t < 64) {
        float L = 0.f;
        for (int cc = 0; cc < nch; ++cc) L += wsL[(size_t)cc * U_N + u0 + t];
        inv[t] = 1.0f / L;
    }
    __syncthreads();

    {
        const int ul = t >> 2, d0 = (t & 3) * 16;
        const int u = u0 + ul;
        f32x4 a4[4];
        #pragma unroll
        for (int j = 0; j < 4; ++j) a4[j] = (f32x4){0.f, 0.f, 0.f, 0.f};
        for (int cc = 0; cc < nch; ++cc) {
            const float* src = wsO + ((size_t)cc * U_N + u) * D_N + d0;
            #pragma unroll
            for (int j = 0; j < 4; ++j) a4[j] += *(const f32x4*)(src + 4 * j);
        }
        const float s = inv[ul];
        #pragma unroll
        for (int j = 0; j < 4; ++j)
            *(f32x4*)&agg[ul][d0 + 4 * j] = a4[j] * s;
    }
    __syncthreads();

    {
        const int ul = t >> 2, o0 = (t & 3) * 16;
        f32x4 acc[4];
        #pragma unroll
        for (int j = 0; j < 4; ++j) acc[j] = (f32x4){0.f, 0.f, 0.f, 0.f};
        for (int d = 0; d < 64; ++d) {
            const float av = agg[ul][d];
            #pragma unroll
            for (int j = 0; j < 4; ++j) {
                f32x4 wv = *(const f32x4*)&Wl[d][o0 + 4 * j];
                acc[j] += wv * av;
            }
        }
        float* dst = out + (size_t)(u0 + ul) * OUT_N + o0;
        #pragma unroll
        for (int j = 0; j < 4; ++j)
            *(f32x4*)(dst + 4 * j) = acc[j];
    }
}

// ---------------------------------------------------------------------------
extern "C" void kernel_launch(void* const* d_in, const int* in_sizes, int n_in,
                              void* d_out, int out_size, void* d_ws, size_t ws_size,
                              hipStream_t stream)
{
    const float* user_emb = (const float*)d_in[0];
    const float* item_emb = (const float*)d_in[1];
    const float* attw     = (const float*)d_in[2];
    const int*   adj      = (const int*)d_in[3];
    float* out = (float*)d_out;

    // ws layout: wsO | wsL | itemH | itemTt
    float*          wsO    = (float*)d_ws;
    float*          wsL    = wsO + (size_t)NCH * U_N * D_N;
    _Float16*       itemH  = (_Float16*)(wsL + (size_t)NCH * U_N);
    unsigned short* itemTt = (unsigned short*)(itemH + (size_t)I_N * D_N);

    prep_items<<<dim3(I_N / 256), 256, 0, stream>>>(item_emb, itemH, itemTt);
    atten_main<<<dim3(NCH, U_N / 64), 256, 0, stream>>>(user_emb, itemH, itemTt, adj,
                                                        wsO, wsL);
    atten_combine<<<dim3(U_N / 64), 256, 0, stream>>>(wsO, wsL, attw, out, NCH);
}

// Round 10
// 728.361 us; speedup vs baseline: 1.0896x; 1.0169x over previous
//
#include <hip/hip_runtime.h>
#include <hip/hip_bf16.h>
#include <math.h>

#define U_N   8192
#define I_N   16384
#define D_N   64
#define OUT_N 64
#define BN    32           // items per iteration tile
#define NCH   8            // item chunks (split-K) -> 1024 blocks, 4/CU
#define ITERS 64           // (I_N/NCH)/BN
#define VN_ST 72           // Vn stride (halves): 144B rows
#define VT_ST 40           // Vt stride (halves): 80B rows, b128-aligned

typedef _Float16 half8  __attribute__((ext_vector_type(8)));
typedef short    bf16x8 __attribute__((ext_vector_type(8)));
typedef short    bf16x4 __attribute__((ext_vector_type(4)));
typedef float    f32x4  __attribute__((ext_vector_type(4)));
typedef int      int4v  __attribute__((ext_vector_type(4)));

static __device__ __forceinline__ unsigned short f2bf(float f) {
    union { __hip_bfloat16 h; unsigned short u; } cv;
    cv.h = __float2bfloat16(f);
    return cv.u;
}
// exp2 (scores are pre-scaled by log2e, so this IS exp)
static __device__ __forceinline__ float fast_exp2(float x) {
#if __has_builtin(__builtin_amdgcn_exp2f)
    return __builtin_amdgcn_exp2f(x);
#else
    return __expf(x * 0.6931471805599453f);
#endif
}
// pack 4 fp32 -> bf16x4 by TRUNCATION (v_perm grabs the high 16 bits of each)
static __device__ __forceinline__ bf16x4 pack4(float a, float b, float c2, float d) {
    union { unsigned u[2]; bf16x4 h; } x;
#if __has_builtin(__builtin_amdgcn_perm)
    x.u[0] = __builtin_amdgcn_perm(__float_as_uint(b), __float_as_uint(a), 0x07060302u);
    x.u[1] = __builtin_amdgcn_perm(__float_as_uint(d), __float_as_uint(c2), 0x07060302u);
#else
    x.u[0] = (__float_as_uint(b) & 0xffff0000u) | (__float_as_uint(a) >> 16);
    x.u[1] = (__float_as_uint(d) & 0xffff0000u) | (__float_as_uint(c2) >> 16);
#endif
    return x.h;
}
// LDS-only barrier: global prefetches stay in flight across it.
static __device__ __forceinline__ void bar() {
    asm volatile("s_waitcnt lgkmcnt(0)\n\ts_barrier" ::: "memory");
}
// PV matmul 16x16x16 bf16: A-operand layout == S^T C-layout (r9-verified).
static __device__ __forceinline__ f32x4 pv_mfma(bf16x4 a, bf16x4 b, f32x4 c) {
#if __has_builtin(__builtin_amdgcn_mfma_f32_16x16x16bf16_1k)
    return __builtin_amdgcn_mfma_f32_16x16x16bf16_1k(a, b, c, 0, 0, 0);
#else
    f32x4 d;
    asm volatile("v_mfma_f32_16x16x16_bf16 %0, %1, %2, %3"
                 : "=v"(d) : "v"(a), "v"(b), "v"(c));
    return d;
#endif
}

// ---------------------------------------------------------------------------
// prep_items: itemH f16 [item][dim]; itemTt bf16 tiled transpose with
// INTERLEAVED slot order (items 0-15 at slots 8q+r, items 16-31 at 8q+4+r)
// so one b128 per (row, q) yields both PV K-group fragments.
// ---------------------------------------------------------------------------
__global__ __launch_bounds__(256)
void prep_items(const float* __restrict__ item,
                _Float16* __restrict__ itemH,
                unsigned short* __restrict__ itemTt)
{
    const int i = blockIdx.x * 256 + threadIdx.x;
    const float* src = item + (size_t)i * D_N;
    f32x4 v[16];
    #pragma unroll
    for (int j = 0; j < 16; ++j) v[j] = *(const f32x4*)(src + 4 * j);

    #pragma unroll
    for (int j = 0; j < 8; ++j) {
        half8 h;
        #pragma unroll
        for (int k = 0; k < 4; ++k) { h[k] = (_Float16)v[2*j][k]; h[4+k] = (_Float16)v[2*j+1][k]; }
        *(half8*)&itemH[(size_t)i * D_N + 8 * j] = h;
    }
    const int il    = i & 31;
    const int islot = 8 * ((il & 15) >> 2) + ((il >> 4) << 2) + (il & 3);
    const size_t tb = (size_t)(i >> 5) * (D_N * 32) + islot;
    #pragma unroll
    for (int d = 0; d < 64; ++d)
        itemTt[tb + (size_t)d * 32] = f2bf(v[d >> 2][d & 3]);
}

// ---------------------------------------------------------------------------
// Named-register pipeline state (arrays/structs/lambdas demote to scratch;
// r3/r4 lesson).
// ---------------------------------------------------------------------------
#define DECL_SET(S) \
    int4v adj##S##a, adj##S##b; \
    half8 vn##S; bf16x8 vt##S;

#define LOAD_ADJ(S, tidx) do { \
    const size_t o_ = (size_t)(tidx) * BN; \
    adj##S##a = *(const int4v*)&adjq[o_];      \
    adj##S##b = *(const int4v*)&adjq[o_ + 16]; \
} while (0)

#define LOAD_TILE(S, tidx) do { \
    const size_t o_ = (size_t)(tidx) * BN; \
    vn##S = *(const half8*)&itemH[(ibase0 + o_ + (t >> 3)) * D_N + (t & 7) * 8]; \
    vt##S = *(const bf16x8*)&itemTt[((ibase0 + o_) >> 5) * (D_N * 32) \
                                    + (size_t)(t >> 2) * 32 + (t & 3) * 8]; \
} while (0)

#define COMMIT(S, bufw) do { \
    *(half8*)&Vn[bufw][(t >> 3) * VN_ST + (t & 7) * 8] = vn##S; \
    *(bf16x8*)&Vt[bufw][(t >> 2) * VT_ST + (t & 3) * 8] = vt##S; \
} while (0)

// S^T = Item * User^T (f16, ufrag pre-scaled by log2e -> T is log2-domain).
// Lane (q,c): T0[r] = items 4q+r, T1[r] = items 16+4q+r, user c.
// Mask applied straight off the adj registers; exp = bare v_exp; P packed by
// truncation; PV fed directly from registers (one b128/row gives both K-groups).
#define COMPUTE_REST(S, bufr) do { \
    half8 a00 = *(const half8*)&Vn[bufr][(c)      * VN_ST      + q * 8]; \
    half8 a01 = *(const half8*)&Vn[bufr][(c)      * VN_ST + 32 + q * 8]; \
    half8 a10 = *(const half8*)&Vn[bufr][(16 + c) * VN_ST      + q * 8]; \
    half8 a11 = *(const half8*)&Vn[bufr][(16 + c) * VN_ST + 32 + q * 8]; \
    bf16x8 w0 = *(const bf16x8*)&Vt[bufr][(c)      * VT_ST + 8 * q]; \
    bf16x8 w1 = *(const bf16x8*)&Vt[bufr][(16 + c) * VT_ST + 8 * q]; \
    bf16x8 w2 = *(const bf16x8*)&Vt[bufr][(32 + c) * VT_ST + 8 * q]; \
    bf16x8 w3 = *(const bf16x8*)&Vt[bufr][(48 + c) * VT_ST + 8 * q]; \
    f32x4 T0 = (f32x4){0.f,0.f,0.f,0.f}; \
    f32x4 T1 = (f32x4){0.f,0.f,0.f,0.f}; \
    T0 = __builtin_amdgcn_mfma_f32_16x16x32_f16(a00, ufrag0, T0, 0, 0, 0); \
    T0 = __builtin_amdgcn_mfma_f32_16x16x32_f16(a01, ufrag1, T0, 0, 0, 0); \
    T1 = __builtin_amdgcn_mfma_f32_16x16x32_f16(a10, ufrag0, T1, 0, 0, 0); \
    T1 = __builtin_amdgcn_mfma_f32_16x16x32_f16(a11, ufrag1, T1, 0, 0, 0); \
    const float e0_ = fast_exp2((adj##S##a[0] != 0) ? T0[0] : 0.0f); \
    const float e1_ = fast_exp2((adj##S##a[1] != 0) ? T0[1] : 0.0f); \
    const float e2_ = fast_exp2((adj##S##a[2] != 0) ? T0[2] : 0.0f); \
    const float e3_ = fast_exp2((adj##S##a[3] != 0) ? T0[3] : 0.0f); \
    const float f0_ = fast_exp2((adj##S##b[0] != 0) ? T1[0] : 0.0f); \
    const float f1_ = fast_exp2((adj##S##b[1] != 0) ? T1[1] : 0.0f); \
    const float f2_ = fast_exp2((adj##S##b[2] != 0) ? T1[2] : 0.0f); \
    const float f3_ = fast_exp2((adj##S##b[3] != 0) ? T1[3] : 0.0f); \
    lc += ((e0_ + e1_) + (e2_ + e3_)) + ((f0_ + f1_) + (f2_ + f3_)); \
    bf16x4 p0 = pack4(e0_, e1_, e2_, e3_); \
    bf16x4 p1 = pack4(f0_, f1_, f2_, f3_); \
    bf16x4 lo0 = __builtin_shufflevector(w0, w0, 0, 1, 2, 3); \
    bf16x4 hi0 = __builtin_shufflevector(w0, w0, 4, 5, 6, 7); \
    bf16x4 lo1 = __builtin_shufflevector(w1, w1, 0, 1, 2, 3); \
    bf16x4 hi1 = __builtin_shufflevector(w1, w1, 4, 5, 6, 7); \
    bf16x4 lo2 = __builtin_shufflevector(w2, w2, 0, 1, 2, 3); \
    bf16x4 hi2 = __builtin_shufflevector(w2, w2, 4, 5, 6, 7); \
    bf16x4 lo3 = __builtin_shufflevector(w3, w3, 0, 1, 2, 3); \
    bf16x4 hi3 = __builtin_shufflevector(w3, w3, 4, 5, 6, 7); \
    O0 = pv_mfma(p0, lo0, O0);  O0 = pv_mfma(p1, hi0, O0); \
    O1 = pv_mfma(p0, lo1, O1);  O1 = pv_mfma(p1, hi1, O1); \
    O2 = pv_mfma(p0, lo2, O2);  O2 = pv_mfma(p1, hi2, O2); \
    O3 = pv_mfma(p0, lo3, O3);  O3 = pv_mfma(p1, hi3, O3); \
} while (0)

// ---------------------------------------------------------------------------
// Main: ping-pong LDS tiles, LDS-only barriers, transposed-S, direct-reg PV.
// Tile j: loaded j-3..j-2, committed j-1, consumed j. adj loaded ~2 ahead.
// ---------------------------------------------------------------------------
__global__ __launch_bounds__(256, 4)
void atten_main(const float* __restrict__ user_emb,
                const _Float16* __restrict__ itemH,
                const unsigned short* __restrict__ itemTt,
                const int*   __restrict__ adj,
                float* __restrict__ wsO,
                float* __restrict__ wsL)
{
    __shared__ _Float16 Vn[2][BN * VN_ST];
    __shared__ short    Vt[2][D_N * VT_ST];

    const int ch   = blockIdx.x;
    const int ub   = blockIdx.y;
    const int t    = threadIdx.x;
    const int w    = t >> 6;
    const int lane = t & 63;
    const int c    = lane & 15;
    const int q    = lane >> 4;

    const int    urow0  = ub * 64 + w * 16;
    const size_t ibase0 = (size_t)ch * (I_N / NCH);

    // user fragments pre-scaled by log2(e): S-MFMA outputs log2-domain scores
    half8 ufrag0, ufrag1;
    {
        const float* up = user_emb + (size_t)(urow0 + c) * D_N + q * 8;
        const float s = 1.44269504088896f;
        f32x4 a0 = *(const f32x4*)(up);
        f32x4 b0 = *(const f32x4*)(up + 4);
        f32x4 a1 = *(const f32x4*)(up + 32);
        f32x4 b1 = *(const f32x4*)(up + 36);
        #pragma unroll
        for (int j = 0; j < 4; ++j) {
            ufrag0[j] = (_Float16)(a0[j] * s); ufrag0[4 + j] = (_Float16)(b0[j] * s);
            ufrag1[j] = (_Float16)(a1[j] * s); ufrag1[4 + j] = (_Float16)(b1[j] * s);
        }
    }

    f32x4 O0 = (f32x4){0.f,0.f,0.f,0.f};
    f32x4 O1 = O0, O2 = O0, O3 = O0;
    float lc = 0.f;

    const int* adjq = adj + (size_t)(urow0 + c) * I_N + ibase0 + 4 * q;

    DECL_SET(A)
    DECL_SET(B)

    LOAD_TILE(A, 0); LOAD_ADJ(A, 0);
    LOAD_TILE(B, 1); LOAD_ADJ(B, 1);
    COMMIT(A, 0);
    LOAD_TILE(A, 2);
    bar();

    for (int k = 0; k < ITERS; k += 2) {
        {   // iter k: consume buf0 + adjA; commit B; reload tileB, adjA
            COMMIT(B, 1);
            LOAD_TILE(B, (k + 3 < ITERS) ? k + 3 : ITERS - 1);
            COMPUTE_REST(A, 0);
            LOAD_ADJ(A, (k + 2 < ITERS) ? k + 2 : ITERS - 1);
            bar();
        }
        {   // iter k+1: consume buf1 + adjB; commit A; reload tileA, adjB
            COMMIT(A, 0);
            LOAD_TILE(A, (k + 4 < ITERS) ? k + 4 : ITERS - 1);
            COMPUTE_REST(B, 1);
            LOAD_ADJ(B, (k + 3 < ITERS) ? k + 3 : ITERS - 1);
            bar();
        }
    }

    // l: lanes c, c+16, c+32, c+48 hold partials for user c
    lc += __shfl_xor(lc, 16);
    lc += __shfl_xor(lc, 32);

    // chunk partials (O C-layout: lane (q,c): rows 4q+r, dims 16nt+c)
    {
        float* d0 = wsO + ((size_t)ch * U_N + urow0 + 4 * q + 0) * D_N;
        float* d1 = wsO + ((size_t)ch * U_N + urow0 + 4 * q + 1) * D_N;
        float* d2 = wsO + ((size_t)ch * U_N + urow0 + 4 * q + 2) * D_N;
        float* d3 = wsO + ((size_t)ch * U_N + urow0 + 4 * q + 3) * D_N;
        d0[c] = O0[0]; d0[16 + c] = O1[0]; d0[32 + c] = O2[0]; d0[48 + c] = O3[0];
        d1[c] = O0[1]; d1[16 + c] = O1[1]; d1[32 + c] = O2[1]; d1[48 + c] = O3[1];
        d2[c] = O0[2]; d2[16 + c] = O1[2]; d2[32 + c] = O2[2]; d2[48 + c] = O3[2];
        d3[c] = O0[3]; d3[16 + c] = O1[3]; d3[32 + c] = O2[3]; d3[48 + c] = O3[3];
    }
    if (q == 0)
        wsL[(size_t)ch * U_N + urow0 + c] = lc;
}

// ---------------------------------------------------------------------------
// Combine: sum chunk partials, normalize, project by attention_weight.
// ---------------------------------------------------------------------------
__global__ __launch_bounds__(256)
void atten_combine(const float* __restrict__ wsO,
                   const float* __restrict__ wsL,
                   const float* __restrict__ attw,
                   float* __restrict__ out,
                   int nch)
{
    __shared__ float inv[64];
    __shared__ float agg[64][68];
    __shared__ float Wl[64][68];

    const int t  = threadIdx.x;
    const int u0 = blockIdx.x * 64;

    {
        const int d = t >> 2, o0 = (t & 3) * 16;
        const float* src = attw + d * OUT_N + o0;
        #pragma unroll
        for (int j = 0; j < 4; ++j)
            *(f32x4*)&Wl[d][o0 + 4 * j] = *(const f32x4*)(src + 4 * j);
    }
    if (t < 64) {
        float L = 0.f;
        for (int cc = 0; cc < nch; ++cc) L += wsL[(size_t)cc * U_N + u0 + t];
        inv[t] = 1.0f / L;
    }
    __syncthreads();

    {
        const int ul = t >> 2, d0 = (t & 3) * 16;
        const int u = u0 + ul;
        f32x4 a4[4];
        #pragma unroll
        for (int j = 0; j < 4; ++j) a4[j] = (f32x4){0.f, 0.f, 0.f, 0.f};
        for (int cc = 0; cc < nch; ++cc) {
            const float* src = wsO + ((size_t)cc * U_N + u) * D_N + d0;
            #pragma unroll
            for (int j = 0; j < 4; ++j) a4[j] += *(const f32x4*)(src + 4 * j);
        }
        const float s = inv[ul];
        #pragma unroll
        for (int j = 0; j < 4; ++j)
            *(f32x4*)&agg[ul][d0 + 4 * j] = a4[j] * s;
    }
    __syncthreads();

    {
        const int ul = t >> 2, o0 = (t & 3) * 16;
        f32x4 acc[4];
        #pragma unroll
        for (int j = 0; j < 4; ++j) acc[j] = (f32x4){0.f, 0.f, 0.f, 0.f};
        for (int d = 0; d < 64; ++d) {
            const float av = agg[ul][d];
            #pragma unroll
            for (int j = 0; j < 4; ++j) {
                f32x4 wv = *(const f32x4*)&Wl[d][o0 + 4 * j];
                acc[j] += wv * av;
            }
        }
        float* dst = out + (size_t)(u0 + ul) * OUT_N + o0;
        #pragma unroll
        for (int j = 0; j < 4; ++j)
            *(f32x4*)(dst + 4 * j) = acc[j];
    }
}

// ---------------------------------------------------------------------------
extern "C" void kernel_launch(void* const* d_in, const int* in_sizes, int n_in,
                              void* d_out, int out_size, void* d_ws, size_t ws_size,
                              hipStream_t stream)
{
    const float* user_emb = (const float*)d_in[0];
    const float* item_emb = (const float*)d_in[1];
    const float* attw     = (const float*)d_in[2];
    const int*   adj      = (const int*)d_in[3];
    float* out = (float*)d_out;

    // ws layout: wsO | wsL | itemH | itemTt
    float*          wsO    = (float*)d_ws;
    float*          wsL    = wsO + (size_t)NCH * U_N * D_N;
    _Float16*       itemH  = (_Float16*)(wsL + (size_t)NCH * U_N);
    unsigned short* itemTt = (unsigned short*)(itemH + (size_t)I_N * D_N);

    prep_items<<<dim3(I_N / 256), 256, 0, stream>>>(item_emb, itemH, itemTt);
    atten_main<<<dim3(NCH, U_N / 64), 256, 0, stream>>>(user_emb, itemH, itemTt, adj,
                                                        wsO, wsL);
    atten_combine<<<dim3(U_N / 64), 256, 0, stream>>>(wsO, wsL, attw, out, NCH);
}